// Round 10
// baseline (444.925 us; speedup 1.0000x reference)
//
#include <hip/hip_runtime.h>
#include <hip/hip_bf16.h>

// RelMultiHeadAttn (Transformer-XL) on MI355X.
// fp32 inputs/outputs; fp16 internal, fp32 accumulate.
// QLEN=1024 MLEN=1024 KLEN=2048 BSZ=2 DMODEL=1024 NH=16 DH=64
// Round 20: R7 base (268.9us best) + V-staging ELIMINATED in attn:
//  - V B-frags load DIRECT from global vt as f16x8 (16B-aligned, 64B-line
//    exact across quads), issued right after s2 -> ~1.5k cycles of cover
//    before PV (R3's direct-load regression had ~300cy cover; this doesn't).
//  - Removes Vs LDS (9216B -> LDS 38912B) => 4 blocks/CU (grid 1024 = exactly
//    4/CU, all resident; was 3). Shortens per-tile chain (no V stage writes,
//    no PV LDS reads). Cost: 4x redundant L2 reads of the 8KB V tile/block
//    (trivial vs 34TB/s L2).
//  - launch_bounds(256,4): VGPR cap 128; live state ~115 (R8 spill lesson:
//    no setprio, prefetch kept minimal K+RK only).
// prep/proj_fused(vt-transpose)/combine/gemm_out byte-identical to R7.

#define QLENC 1024
#define KLENC 2048
#define BSZC 2
#define DMODELC 1024
#define NHC 16
#define DHC 64

typedef _Float16 half_t;
typedef __attribute__((ext_vector_type(8))) _Float16 f16x8;
typedef __attribute__((ext_vector_type(4))) float f32x4;

// async global->LDS, 16B per lane. LDS dest is wave-uniform base + lane*16;
// global src is per-lane.
__device__ __forceinline__ void async_copy16(const half_t* g, half_t* l) {
    __builtin_amdgcn_global_load_lds(
        (const __attribute__((address_space(1))) void*)g,
        (__attribute__((address_space(3))) void*)l,
        16, 0, 0);
}

// ---------------------------------------------------------------- prep
// blocks [0,2048): cvt w->wh; [2048,3072): cvt r->rh;
// [3072,4352): transpose Wq/Wkv/Wr/Wo fp32 -> fp16 [N,K].
__global__ __launch_bounds__(256) void prep(
    const float* __restrict__ w, const float* __restrict__ r,
    const float* __restrict__ Wq, const float* __restrict__ Wkv,
    const float* __restrict__ Wr, const float* __restrict__ Wo,
    half_t* __restrict__ wh, half_t* __restrict__ rh,
    half_t* __restrict__ WqT, half_t* __restrict__ WkvT,
    half_t* __restrict__ WrT, half_t* __restrict__ WoT) {
    __shared__ __attribute__((aligned(16))) half_t T[64][72];
    int bx = blockIdx.x, t = threadIdx.x;
    if (bx < 3072) {
        const float* s; half_t* d; size_t base;
        if (bx < 2048) { s = w; d = wh; base = (size_t)bx * 2048; }
        else           { s = r; d = rh; base = (size_t)(bx - 2048) * 2048; }
        size_t i = base + (size_t)t * 8;
        const float4* sp = (const float4*)(s + i);
        float4 f0 = sp[0], f1 = sp[1];
        half_t h[8];
        h[0] = (half_t)f0.x; h[1] = (half_t)f0.y; h[2] = (half_t)f0.z; h[3] = (half_t)f0.w;
        h[4] = (half_t)f1.x; h[5] = (half_t)f1.y; h[6] = (half_t)f1.z; h[7] = (half_t)f1.w;
        *(uint4*)(d + i) = *(uint4*)&h[0];
        return;
    }
    int b2 = bx - 3072;
    const float* W; half_t* Wt; int N, tx, ty;
    if (b2 < 256)       { W = Wq;  Wt = WqT;  N = 1024; tx = b2 & 15;         ty = b2 >> 4; }
    else if (b2 < 768)  { int c = b2 - 256;  W = Wkv; Wt = WkvT; N = 2048; tx = c & 31; ty = c >> 5; }
    else if (b2 < 1024) { int c = b2 - 768;  W = Wr;  Wt = WrT;  N = 1024; tx = c & 15; ty = c >> 4; }
    else                { int c = b2 - 1024; W = Wo;  Wt = WoT;  N = 1024; tx = c & 15; ty = c >> 4; }
    const int K = 1024;
    int n0 = tx * 64, k0 = ty * 64;
    int r_ = t >> 2, c_ = (t & 3) << 4;
    const float4* s = (const float4*)&W[(size_t)(k0 + r_) * N + n0 + c_];
    float4 f0 = s[0], f1 = s[1], f2 = s[2], f3 = s[3];
    half_t h[16];
    h[0] = (half_t)f0.x; h[1] = (half_t)f0.y; h[2] = (half_t)f0.z; h[3] = (half_t)f0.w;
    h[4] = (half_t)f1.x; h[5] = (half_t)f1.y; h[6] = (half_t)f1.z; h[7] = (half_t)f1.w;
    h[8] = (half_t)f2.x; h[9] = (half_t)f2.y; h[10] = (half_t)f2.z; h[11] = (half_t)f2.w;
    h[12] = (half_t)f3.x; h[13] = (half_t)f3.y; h[14] = (half_t)f3.z; h[15] = (half_t)f3.w;
    *(uint4*)&T[r_][c_] = *(uint4*)&h[0];
    *(uint4*)&T[r_][c_ + 8] = *(uint4*)&h[8];
    __syncthreads();
    half_t vals[16];
#pragma unroll
    for (int u = 0; u < 16; u++) vals[u] = T[c_ + u][r_];
    *(uint4*)&Wt[(size_t)(n0 + r_) * K + k0 + c_] = *(uint4*)&vals[0];
    *(uint4*)&Wt[(size_t)(n0 + r_) * K + k0 + c_ + 8] = *(uint4*)&vals[8];
}

// ---------------------------------------------------------------- fused projections
// One launch, 768 blocks, 128x128 tiles, K=1024, m97-style staging.
// blocks [0,512): kv-proj -> kh [b][n][j][d], vt [b][n][d][j]
// blocks [512,640): q-proj -> qw(+rwb), qr(+rrb) head-split
// blocks [640,768): r-proj -> rk [n][t][d]
// V-blocks (tx>=8) transpose C through LDS -> coalesced vt stores.
__global__ __launch_bounds__(256) void proj_fused(
    const half_t* __restrict__ wh, const half_t* __restrict__ rh,
    const half_t* __restrict__ WqT, const half_t* __restrict__ WkvT,
    const half_t* __restrict__ WrT,
    half_t* __restrict__ qw, half_t* __restrict__ qr,
    half_t* __restrict__ kh, half_t* __restrict__ vt,
    half_t* __restrict__ rk,
    const float* __restrict__ rwb, const float* __restrict__ rrb) {
    // staging (2x 128x64 = 32KB) aliased with transpose buffer (128x136 = 34KB)
    __shared__ __attribute__((aligned(16))) half_t SM[128 * 136];
    half_t (*As)[64] = (half_t(*)[64])SM;
    half_t (*Bs)[64] = (half_t(*)[64])(SM + 128 * 64);
    half_t (*LT)[136] = (half_t(*)[136])SM;

    int bid = blockIdx.x;
    int mode, tx, ty;
    const half_t* A; const half_t* Bt;
    if (bid < 512)      { mode = 1; tx = bid & 15, ty = bid >> 4; A = wh; Bt = WkvT; }
    else if (bid < 640) { int c = bid - 512; mode = 0; tx = c & 7; ty = c >> 3;
                          A = wh + (size_t)QLENC * BSZC * DMODELC; Bt = WqT; }
    else                { int c = bid - 640; mode = 2; tx = c & 7; ty = c >> 3;
                          A = rh; Bt = WrT; }

    int t = threadIdx.x;
    int w = t >> 6, ln = t & 63, quad = ln >> 4, l15 = ln & 15;
    int m0 = ty * 128, n0 = tx * 128;
    int rbase = 64 * (w >> 1), cbase = 64 * (w & 1);
    int lrow = ln >> 3, lcol = (ln & 7) * 8;

    f32x4 acc[4][4];
#pragma unroll
    for (int i = 0; i < 4; i++)
#pragma unroll
        for (int j = 0; j < 4; j++) acc[i][j] = (f32x4){0.f, 0.f, 0.f, 0.f};

    for (int k0 = 0; k0 < 1024; k0 += 64) {
        __syncthreads();
#pragma unroll
        for (int j = 0; j < 4; j++) {
            int r8 = w * 32 + j * 8;
            async_copy16(&A[(size_t)(m0 + r8 + lrow) * 1024 + k0 + lcol], &As[r8][0]);
            async_copy16(&Bt[(size_t)(n0 + r8 + lrow) * 1024 + k0 + lcol], &Bs[r8][0]);
        }
        __syncthreads();
#pragma unroll
        for (int kk = 0; kk < 2; kk++) {
            f16x8 af[4], bfr[4];
#pragma unroll
            for (int rb = 0; rb < 4; rb++)
                af[rb] = *(const f16x8*)&As[rbase + rb * 16 + l15][kk * 32 + quad * 8];
#pragma unroll
            for (int cb = 0; cb < 4; cb++)
                bfr[cb] = *(const f16x8*)&Bs[cbase + cb * 16 + l15][kk * 32 + quad * 8];
#pragma unroll
            for (int rb = 0; rb < 4; rb++)
#pragma unroll
                for (int cb = 0; cb < 4; cb++)
                    acc[rb][cb] = __builtin_amdgcn_mfma_f32_16x16x32_f16(
                        af[rb], bfr[cb], acc[rb][cb], 0, 0, 0);
        }
    }

    if (mode == 1 && tx >= 8) {
        // V-block: transpose C through LDS, store vt coalesced.
        __syncthreads();  // staging reads done; safe to overwrite SM
#pragma unroll
        for (int rb = 0; rb < 4; rb++)
#pragma unroll
            for (int cb = 0; cb < 4; cb++)
#pragma unroll
                for (int reg = 0; reg < 4; reg++) {
                    int lr_ = rbase + 16 * rb + quad * 4 + reg;  // m-dir 0..127
                    int lc_ = cbase + 16 * cb + l15;             // n-dir 0..127
                    LT[lc_][lr_] = (half_t)acc[rb][cb][reg];
                }
        __syncthreads();
        // 8 passes; 8 lanes per (lc_, b) pair write one 128B p-run as uint4s.
#pragma unroll
        for (int pass = 0; pass < 8; pass++) {
            int g = pass * 32 + (t >> 3), s_ = t & 7;
            int lc_ = g >> 1, b_ = g & 1;
            half_t tmp[8];
#pragma unroll
            for (int k = 0; k < 8; k++) tmp[k] = LT[lc_][b_ + 2 * (s_ * 8 + k)];
            int gc = n0 - 1024 + lc_;
            int hh = gc >> 6, d_ = gc & 63;
            int p0 = (m0 >> 1) + s_ * 8;
            *(uint4*)&vt[(((size_t)(b_ * NHC + hh)) * DHC + d_) * KLENC + p0] = *(uint4*)&tmp[0];
        }
        return;
    }

#pragma unroll
    for (int rb = 0; rb < 4; rb++)
#pragma unroll
        for (int cb = 0; cb < 4; cb++)
#pragma unroll
            for (int reg = 0; reg < 4; reg++) {
                int gr = m0 + rbase + 16 * rb + quad * 4 + reg;
                int gc = n0 + cbase + 16 * cb + l15;
                float v = acc[rb][cb][reg];
                if (mode == 1) {
                    int p_ = gr >> 1, b_ = gr & 1;
                    int n_ = gc >> 6, d_ = gc & 63;
                    kh[(((size_t)(b_ * NHC + n_)) * KLENC + p_) * DHC + d_] = (half_t)v;
                } else if (mode == 0) {
                    int p_ = gr >> 1, b_ = gr & 1, n_ = gc >> 6, d_ = gc & 63;
                    size_t idx = (((size_t)(b_ * NHC + n_)) * QLENC + p_) * DHC + d_;
                    qw[idx] = (half_t)(v + rwb[gc]);
                    qr[idx] = (half_t)(v + rrb[gc]);
                } else {
                    int n_ = gc >> 6, d_ = gc & 63;
                    rk[(((size_t)n_) * KLENC + gr) * DHC + d_] = (half_t)v;
                }
            }
}

// ---------------------------------------------------------------- out GEMM
__global__ __launch_bounds__(256) void gemm_out(
    const half_t* __restrict__ A, const half_t* __restrict__ Bt,
    float* __restrict__ o) {
    __shared__ __attribute__((aligned(16))) half_t As[128][64];
    __shared__ __attribute__((aligned(16))) half_t Bs[128][64];

    int t = threadIdx.x;
    int w = t >> 6, ln = t & 63, quad = ln >> 4, l15 = ln & 15;
    int m0 = blockIdx.y * 128, n0 = blockIdx.x * 128;
    int rbase = 64 * (w >> 1), cbase = 64 * (w & 1);
    int lrow = ln >> 3, lcol = (ln & 7) * 8;

    f32x4 acc[4][4];
#pragma unroll
    for (int i = 0; i < 4; i++)
#pragma unroll
        for (int j = 0; j < 4; j++) acc[i][j] = (f32x4){0.f, 0.f, 0.f, 0.f};

    for (int k0 = 0; k0 < 1024; k0 += 64) {
        __syncthreads();
#pragma unroll
        for (int j = 0; j < 4; j++) {
            int r8 = w * 32 + j * 8;
            async_copy16(&A[(size_t)(m0 + r8 + lrow) * 1024 + k0 + lcol], &As[r8][0]);
            async_copy16(&Bt[(size_t)(n0 + r8 + lrow) * 1024 + k0 + lcol], &Bs[r8][0]);
        }
        __syncthreads();
#pragma unroll
        for (int kk = 0; kk < 2; kk++) {
            f16x8 af[4], bfr[4];
#pragma unroll
            for (int rb = 0; rb < 4; rb++)
                af[rb] = *(const f16x8*)&As[rbase + rb * 16 + l15][kk * 32 + quad * 8];
#pragma unroll
            for (int cb = 0; cb < 4; cb++)
                bfr[cb] = *(const f16x8*)&Bs[cbase + cb * 16 + l15][kk * 32 + quad * 8];
#pragma unroll
            for (int rb = 0; rb < 4; rb++)
#pragma unroll
                for (int cb = 0; cb < 4; cb++)
                    acc[rb][cb] = __builtin_amdgcn_mfma_f32_16x16x32_f16(
                        af[rb], bfr[cb], acc[rb][cb], 0, 0, 0);
        }
    }

#pragma unroll
    for (int rb = 0; rb < 4; rb++)
#pragma unroll
        for (int cb = 0; cb < 4; cb++)
#pragma unroll
            for (int reg = 0; reg < 4; reg++) {
                int gr = m0 + rbase + 16 * rb + quad * 4 + reg;
                int gc = n0 + cbase + 16 * cb + l15;
                o[(size_t)gr * 1024 + gc] = acc[rb][cb][reg];
            }
}

// ---------------------------------------------------------------- fused attention
// One block per (head, 64-row q tile, batch, K-split s). Split s handles
// jt in [s*16, s*16+16). Body = round-7 structure with Vs LDS removed:
// V B-frags load direct from global vt (issued after s2, consumed at PV,
// ~1.5k cycles of cover). K/RK reg-staged into LDS, 2 barriers/tile,
// next-tile K/RK prefetch after s2. Windowed T = Qr @ rk[window]^T
// implements rel_shift:
//   delta = j-i: delta<=1024 -> qr_i . rk[1023+delta]   (window mb = 960+D)
//                delta==1025 -> 0
//                delta>=1026 -> qr_{i+1} . rk[delta-1026] (window mb = D-1089)
// Wave w computes T col-tiles {3-w..7-w}; per-wave TP[16][88], local col =
// 15+jc-ic_local. No-max softmax: p = exp(s) raw; partial unnormalized f32 O
// + row sums stored; combine kernel normalizes (exact).
// LDS 38912B -> 4 blocks/CU (grid 1024 = exactly 4/CU, all resident).
__global__ __launch_bounds__(256, 4) void attn_fused(
    const half_t* __restrict__ qw, const half_t* __restrict__ qr,
    const half_t* __restrict__ kh, const half_t* __restrict__ vt,
    const half_t* __restrict__ rk, float* __restrict__ po,
    float* __restrict__ pl) {
    __shared__ __attribute__((aligned(16))) half_t Ks[64][72];
    __shared__ __attribute__((aligned(16))) half_t RKs[128][72];
    __shared__ __attribute__((aligned(16))) half_t TP[4][16][88];

    int n = blockIdx.x, i0 = blockIdx.y * 64;
    int z = blockIdx.z, b = z >> 1, s = z & 1;
    int jt0 = s * 16, jt1 = jt0 + 16;
    int t = threadIdx.x, w = t >> 6, ln = t & 63, quad = ln >> 4, l15 = ln & 15;
    int lr = t >> 2, lc = (t & 3) << 4;
    int q4 = quad * 4;            // local row base within the wave's 16 rows
    int wq = w * 16 + q4;
    size_t bn = (size_t)(b * NHC + n);
    const half_t* rkn = rk + (size_t)n * KLENC * DHC;
    half_t (*TPw)[88] = TP[w];

    // Q/Qr fragments: wave-local rows -> registers, loaded once per block.
    f16x8 aqw[2], aq1[2], aq2[2];
    {
        int row1 = i0 + w * 16 + l15;
        int row2 = row1 + 1; if (row2 > QLENC - 1) row2 = QLENC - 1;  // clamped row never contributes
#pragma unroll
        for (int kk = 0; kk < 2; kk++) {
            aqw[kk] = *(const f16x8*)&qw[((bn * QLENC) + row1) * DHC + kk * 32 + quad * 8];
            aq1[kk] = *(const f16x8*)&qr[((bn * QLENC) + row1) * DHC + kk * 32 + quad * 8];
            aq2[kk] = *(const f16x8*)&qr[((bn * QLENC) + row2) * DHC + kk * 32 + quad * 8];
        }
    }

    int rrl = t >> 1, rh = (t & 1) * 32;
    // per-lane V fragment base: row = d index (varies by db), col within tile
    const half_t* vbase = vt + ((bn * DHC) + l15) * KLENC + quad * 8;

    // prefetch tile jt0 (K + RK window; V is loaded direct per-tile)
    uint4 pk0, pk1, pr0, pr1, pr2, pr3;
    {
        int j0 = jt0 * 64;
        int D = j0 - i0;
        int mb = (D <= 1024) ? (960 + D) : (D - 1089);
        int rrow = mb + rrl; rrow = rrow < 0 ? 0 : (rrow > KLENC - 1 ? KLENC - 1 : rrow);
        const uint4* ks = (const uint4*)&kh[((bn * KLENC) + j0 + lr) * DHC + lc];
        pk0 = ks[0]; pk1 = ks[1];
        const uint4* rs = (const uint4*)&rkn[(size_t)rrow * DHC + rh];
        pr0 = rs[0]; pr1 = rs[1]; pr2 = rs[2]; pr3 = rs[3];
    }

    f32x4 O[4];
#pragma unroll
    for (int i = 0; i < 4; i++) O[i] = (f32x4){0.f, 0.f, 0.f, 0.f};
    float lsum[4] = {0.f, 0.f, 0.f, 0.f};
    const float scale = 0.125f;  // 1/sqrt(64)

    for (int jt = jt0; jt < jt1; jt++) {
        int j0 = jt * 64;
        int D = j0 - i0;
        bool need1 = (D <= 1024), need2 = (D >= 1024);  // block-uniform

        __syncthreads();  // s1: prior-iter cross-wave LDS reads done (drains prefetch vmcnt)
        *(uint4*)&Ks[lr][lc] = pk0; *(uint4*)&Ks[lr][lc + 8] = pk1;
        *(uint4*)&RKs[rrl][rh] = pr0;      *(uint4*)&RKs[rrl][rh + 8] = pr1;
        *(uint4*)&RKs[rrl][rh + 16] = pr2; *(uint4*)&RKs[rrl][rh + 24] = pr3;
        __syncthreads();  // s2

        // V fragments for THIS tile: direct from global, issued early so L2
        // latency hides under QK/T/softmax (~1.5k cycles before PV consumes).
        f16x8 vfrag[8];
#pragma unroll
        for (int db = 0; db < 4; db++)
#pragma unroll
            for (int kk = 0; kk < 2; kk++)
                vfrag[db * 2 + kk] =
                    *(const f16x8*)(vbase + (size_t)(db * 16) * KLENC + j0 + kk * 32);

        // prefetch next tile's K/RK; latency hides under this tile's compute
        if (jt + 1 < jt1) {
            int j0n = j0 + 64, Dn = j0n - i0;
            int mbn = (Dn <= 1024) ? (960 + Dn) : (Dn - 1089);
            int rrown = mbn + rrl; rrown = rrown < 0 ? 0 : (rrown > KLENC - 1 ? KLENC - 1 : rrown);
            const uint4* ks = (const uint4*)&kh[((bn * KLENC) + j0n + lr) * DHC + lc];
            pk0 = ks[0]; pk1 = ks[1];
            const uint4* rs = (const uint4*)&rkn[(size_t)rrown * DHC + rh];
            pr0 = rs[0]; pr1 = rs[1]; pr2 = rs[2]; pr3 = rs[3];
        }

        f32x4 sa[4];
#pragma unroll
        for (int cb = 0; cb < 4; cb++) sa[cb] = (f32x4){0.f, 0.f, 0.f, 0.f};
#pragma unroll
        for (int kk = 0; kk < 2; kk++) {
#pragma unroll
            for (int cb = 0; cb < 4; cb++) {
                f16x8 bk = *(const f16x8*)&Ks[cb * 16 + l15][kk * 32 + quad * 8];
                sa[cb] = __builtin_amdgcn_mfma_f32_16x16x32_f16(aqw[kk], bk, sa[cb], 0, 0, 0);
            }
        }

        float bdv[4][4];
#pragma unroll
        for (int cb = 0; cb < 4; cb++)
#pragma unroll
            for (int reg = 0; reg < 4; reg++) bdv[cb][reg] = 0.f;

        if (need1) {
            f32x4 tacc[5];
#pragma unroll
            for (int c = 0; c < 5; c++) tacc[c] = (f32x4){0.f, 0.f, 0.f, 0.f};
#pragma unroll
            for (int kk = 0; kk < 2; kk++) {
#pragma unroll
                for (int c = 0; c < 5; c++) {
                    f16x8 bk = *(const f16x8*)&RKs[(3 - w + c) * 16 + l15][kk * 32 + quad * 8];
                    tacc[c] = __builtin_amdgcn_mfma_f32_16x16x32_f16(aq1[kk], bk, tacc[c], 0, 0, 0);
                }
            }
            // wave-local write -> gather (per-wave TP, local col = c*16+l15)
#pragma unroll
            for (int c = 0; c < 5; c++)
#pragma unroll
                for (int reg = 0; reg < 4; reg++)
                    TPw[q4 + reg][c * 16 + l15] = (half_t)tacc[c][reg];
#pragma unroll
            for (int reg = 0; reg < 4; reg++) {
                int icl = q4 + reg, ic = w * 16 + icl;
#pragma unroll
                for (int cb = 0; cb < 4; cb++) {
                    int jc = cb * 16 + l15;
                    int delta = D + jc - ic;
                    if (delta <= 1024) bdv[cb][reg] = (float)TPw[icl][15 + jc - icl];
                }
            }
        }
        if (need2) {
            if (need1) {  // mixed tile (D==1024): restage window 2 (cross-wave)
                int mb2 = D - 1089;
                int rrow2 = mb2 + rrl; rrow2 = rrow2 < 0 ? 0 : (rrow2 > KLENC - 1 ? KLENC - 1 : rrow2);
                const uint4* rs2 = (const uint4*)&rkn[(size_t)rrow2 * DHC + rh];
                uint4 t0 = rs2[0], t1 = rs2[1], t2 = rs2[2], t3 = rs2[3];
                __syncthreads();
                *(uint4*)&RKs[rrl][rh] = t0;      *(uint4*)&RKs[rrl][rh + 8] = t1;
                *(uint4*)&RKs[rrl][rh + 16] = t2; *(uint4*)&RKs[rrl][rh + 24] = t3;
                __syncthreads();
            }
            f32x4 tacc[5];
#pragma unroll
            for (int c = 0; c < 5; c++) tacc[c] = (f32x4){0.f, 0.f, 0.f, 0.f};
#pragma unroll
            for (int kk = 0; kk < 2; kk++) {
#pragma unroll
                for (int c = 0; c < 5; c++) {
                    f16x8 bk = *(const f16x8*)&RKs[(3 - w + c) * 16 + l15][kk * 32 + quad * 8];
                    tacc[c] = __builtin_amdgcn_mfma_f32_16x16x32_f16(aq2[kk], bk, tacc[c], 0, 0, 0);
                }
            }
#pragma unroll
            for (int c = 0; c < 5; c++)
#pragma unroll
                for (int reg = 0; reg < 4; reg++)
                    TPw[q4 + reg][c * 16 + l15] = (half_t)tacc[c][reg];
#pragma unroll
            for (int reg = 0; reg < 4; reg++) {
                int icl = q4 + reg, ic = w * 16 + icl;
#pragma unroll
                for (int cb = 0; cb < 4; cb++) {
                    int jc = cb * 16 + l15;
                    int delta = D + jc - ic;
                    if (delta >= 1026) bdv[cb][reg] = (float)TPw[icl][15 + jc - icl];
                }
            }
        }

        // no-max softmax: p = exp(score), straight accumulate
        float p[4][4];
#pragma unroll
        for (int reg = 0; reg < 4; reg++) {
            float ps = 0.f;
#pragma unroll
            for (int cb = 0; cb < 4; cb++) {
                float e = __expf((sa[cb][reg] + bdv[cb][reg]) * scale);
                e = fminf(e, 60000.f);  // fp16-inf insurance
                p[cb][reg] = e; ps += e;
            }
            lsum[reg] += ps;
        }

        // P: wave-local C-layout -> A-layout round trip (no barrier)
#pragma unroll
        for (int cb = 0; cb < 4; cb++)
#pragma unroll
            for (int reg = 0; reg < 4; reg++)
                TPw[q4 + reg][cb * 16 + l15] = (half_t)p[cb][reg];
#pragma unroll
        for (int kk = 0; kk < 2; kk++) {
            f16x8 pa = *(const f16x8*)&TPw[l15][kk * 32 + quad * 8];
#pragma unroll
            for (int db = 0; db < 4; db++) {
                O[db] = __builtin_amdgcn_mfma_f32_16x16x32_f16(pa, vfrag[db * 2 + kk], O[db], 0, 0, 0);
            }
        }
    }

    // store unnormalized partials: po[s][bn][i][d] f32, pl[s][bn][i] row-sums
    size_t pobase = ((size_t)s * 32 + bn) * QLENC;
#pragma unroll
    for (int db = 0; db < 4; db++)
#pragma unroll
        for (int reg = 0; reg < 4; reg++)
            po[(pobase + i0 + wq + reg) * 64 + db * 16 + l15] = O[db][reg];
#pragma unroll
    for (int reg = 0; reg < 4; reg++) {
        float tot = lsum[reg];
#pragma unroll
        for (int off = 1; off < 16; off <<= 1) tot += __shfl_xor(tot, off, 64);
        if (l15 == 0) pl[pobase + i0 + wq + reg] = tot;
    }
}

// ---------------------------------------------------------------- combine
// av[i][b][n*64+d] = (po0 + po1) / (pl0 + pl1). 262144 threads, 8 d each.
__global__ __launch_bounds__(256) void combine(
    const float* __restrict__ po, const float* __restrict__ pl,
    half_t* __restrict__ av) {
    int gid = blockIdx.x * 256 + threadIdx.x;
    int d0 = (gid & 7) * 8;
    int i = (gid >> 3) & 1023;
    int bn = gid >> 13;
    size_t rowoff = (size_t)bn * QLENC + i;
    size_t base = rowoff * 64 + d0;
    const size_t S = (size_t)32 * QLENC * 64;
    float4 a0 = *(const float4*)&po[base];
    float4 a1 = *(const float4*)&po[base + 4];
    float4 b0 = *(const float4*)&po[S + base];
    float4 b1 = *(const float4*)&po[S + base + 4];
    float invl = 1.0f / (pl[rowoff] + pl[(size_t)32 * QLENC + rowoff]);
    half_t h[8];
    h[0] = (half_t)((a0.x + b0.x) * invl); h[1] = (half_t)((a0.y + b0.y) * invl);
    h[2] = (half_t)((a0.z + b0.z) * invl); h[3] = (half_t)((a0.w + b0.w) * invl);
    h[4] = (half_t)((a1.x + b1.x) * invl); h[5] = (half_t)((a1.y + b1.y) * invl);
    h[6] = (half_t)((a1.z + b1.z) * invl); h[7] = (half_t)((a1.w + b1.w) * invl);
    int b = bn >> 4, n = bn & 15;
    *(uint4*)&av[((size_t)i * BSZC + b) * DMODELC + n * 64 + d0] = *(uint4*)&h[0];
}

// ---------------------------------------------------------------- launch
extern "C" void kernel_launch(void* const* d_in, const int* in_sizes, int n_in,
                              void* d_out, int out_size, void* d_ws, size_t ws_size,
                              hipStream_t stream) {
    const float* w   = (const float*)d_in[0];
    const float* r   = (const float*)d_in[1];
    const float* rwb = (const float*)d_in[2];
    const float* rrb = (const float*)d_in[3];
    const float* Wq  = (const float*)d_in[4];
    const float* Wkv = (const float*)d_in[5];
    const float* Wr  = (const float*)d_in[6];
    const float* Wo  = (const float*)d_in[7];
    float* out = (float*)d_out;

    half_t* ws = (half_t*)d_ws;
    half_t* qw   = ws; ws += (size_t)BSZC * NHC * QLENC * DHC;
    half_t* qr   = ws; ws += (size_t)BSZC * NHC * QLENC * DHC;
    half_t* kh   = ws; ws += (size_t)BSZC * NHC * KLENC * DHC;
    half_t* vt   = ws; ws += (size_t)BSZC * NHC * KLENC * DHC;
    half_t* rk   = ws; ws += (size_t)NHC * KLENC * DHC;
    half_t* av   = ws; ws += (size_t)QLENC * BSZC * DMODELC;
    half_t* WoT  = ws; ws += (size_t)DMODELC * DMODELC;   // live through gemm_out
    half_t* WqT  = ws; ws += (size_t)DMODELC * DMODELC;   // dead after proj_fused
    half_t* WkvT = ws; ws += (size_t)2 * DMODELC * DMODELC;
    half_t* WrT  = ws; ws += (size_t)DMODELC * DMODELC;
    half_t* wh   = ws; ws += (size_t)KLENC * BSZC * DMODELC;
    half_t* rh   = ws; ws += (size_t)KLENC * DMODELC;

    // attn partials alias the dead region WqT..rh (20MB >= 16.25MB needed):
    // po: 2 splits x 32 bn x 1024 i x 64 d f32 (16MB), pl: 2x32x1024 f32.
    float* po = (float*)WqT;
    float* pl = po + (size_t)2 * 32 * QLENC * 64;

    dim3 blk(256);
    prep<<<dim3(4352), blk, 0, stream>>>(w, r, Wq, Wkv, Wr, Wo,
                                         wh, rh, WqT, WkvT, WrT, WoT);
    proj_fused<<<dim3(768), blk, 0, stream>>>(
        wh, rh, WqT, WkvT, WrT, qw, qr, kh, vt, rk, rwb, rrb);
    attn_fused<<<dim3(NHC, QLENC / 64, BSZC * 2), blk, 0, stream>>>(
        qw, qr, kh, vt, rk, po, pl);
    combine<<<dim3(1024), blk, 0, stream>>>(po, pl, av);
    gemm_out<<<dim3(8, 16), blk, 0, stream>>>(av, WoT, out);

    (void)in_sizes; (void)n_in; (void)out_size; (void)ws_size;
}

// Round 11
// 267.436 us; speedup vs baseline: 1.6637x; 1.6637x over previous
//
#include <hip/hip_runtime.h>
#include <hip/hip_bf16.h>

// RelMultiHeadAttn (Transformer-XL) on MI355X.
// fp32 inputs/outputs; fp16 internal, fp32 accumulate.
// QLEN=1024 MLEN=1024 KLEN=2048 BSZ=2 DMODEL=1024 NH=16 DH=64
// Round 21: REVERT to round-17/R7 config (268.9us best; R10's V-direct
// spilled under launch_bounds(256,4): VGPR capped at 64, 634MB scratch
// writes). One isolated fix: gemm_out was 128 blocks on 256 CUs (half GPU
// idle) -> retiled 128x128 to 64x128 (grid 8x32 = 256 blocks, 1/CU, all
// CUs active). As 64x64 + Bs 128x64 = 24KB LDS, per-wave 32x64 (acc[2][4]).
// attn/prep/proj_fused/combine byte-identical to R7.

#define QLENC 1024
#define KLENC 2048
#define BSZC 2
#define DMODELC 1024
#define NHC 16
#define DHC 64

typedef _Float16 half_t;
typedef __attribute__((ext_vector_type(8))) _Float16 f16x8;
typedef __attribute__((ext_vector_type(4))) float f32x4;

// async global->LDS, 16B per lane. LDS dest is wave-uniform base + lane*16;
// global src is per-lane.
__device__ __forceinline__ void async_copy16(const half_t* g, half_t* l) {
    __builtin_amdgcn_global_load_lds(
        (const __attribute__((address_space(1))) void*)g,
        (__attribute__((address_space(3))) void*)l,
        16, 0, 0);
}

// ---------------------------------------------------------------- prep
// blocks [0,2048): cvt w->wh; [2048,3072): cvt r->rh;
// [3072,4352): transpose Wq/Wkv/Wr/Wo fp32 -> fp16 [N,K].
__global__ __launch_bounds__(256) void prep(
    const float* __restrict__ w, const float* __restrict__ r,
    const float* __restrict__ Wq, const float* __restrict__ Wkv,
    const float* __restrict__ Wr, const float* __restrict__ Wo,
    half_t* __restrict__ wh, half_t* __restrict__ rh,
    half_t* __restrict__ WqT, half_t* __restrict__ WkvT,
    half_t* __restrict__ WrT, half_t* __restrict__ WoT) {
    __shared__ __attribute__((aligned(16))) half_t T[64][72];
    int bx = blockIdx.x, t = threadIdx.x;
    if (bx < 3072) {
        const float* s; half_t* d; size_t base;
        if (bx < 2048) { s = w; d = wh; base = (size_t)bx * 2048; }
        else           { s = r; d = rh; base = (size_t)(bx - 2048) * 2048; }
        size_t i = base + (size_t)t * 8;
        const float4* sp = (const float4*)(s + i);
        float4 f0 = sp[0], f1 = sp[1];
        half_t h[8];
        h[0] = (half_t)f0.x; h[1] = (half_t)f0.y; h[2] = (half_t)f0.z; h[3] = (half_t)f0.w;
        h[4] = (half_t)f1.x; h[5] = (half_t)f1.y; h[6] = (half_t)f1.z; h[7] = (half_t)f1.w;
        *(uint4*)(d + i) = *(uint4*)&h[0];
        return;
    }
    int b2 = bx - 3072;
    const float* W; half_t* Wt; int N, tx, ty;
    if (b2 < 256)       { W = Wq;  Wt = WqT;  N = 1024; tx = b2 & 15;         ty = b2 >> 4; }
    else if (b2 < 768)  { int c = b2 - 256;  W = Wkv; Wt = WkvT; N = 2048; tx = c & 31; ty = c >> 5; }
    else if (b2 < 1024) { int c = b2 - 768;  W = Wr;  Wt = WrT;  N = 1024; tx = c & 15; ty = c >> 4; }
    else                { int c = b2 - 1024; W = Wo;  Wt = WoT;  N = 1024; tx = c & 15; ty = c >> 4; }
    const int K = 1024;
    int n0 = tx * 64, k0 = ty * 64;
    int r_ = t >> 2, c_ = (t & 3) << 4;
    const float4* s = (const float4*)&W[(size_t)(k0 + r_) * N + n0 + c_];
    float4 f0 = s[0], f1 = s[1], f2 = s[2], f3 = s[3];
    half_t h[16];
    h[0] = (half_t)f0.x; h[1] = (half_t)f0.y; h[2] = (half_t)f0.z; h[3] = (half_t)f0.w;
    h[4] = (half_t)f1.x; h[5] = (half_t)f1.y; h[6] = (half_t)f1.z; h[7] = (half_t)f1.w;
    h[8] = (half_t)f2.x; h[9] = (half_t)f2.y; h[10] = (half_t)f2.z; h[11] = (half_t)f2.w;
    h[12] = (half_t)f3.x; h[13] = (half_t)f3.y; h[14] = (half_t)f3.z; h[15] = (half_t)f3.w;
    *(uint4*)&T[r_][c_] = *(uint4*)&h[0];
    *(uint4*)&T[r_][c_ + 8] = *(uint4*)&h[8];
    __syncthreads();
    half_t vals[16];
#pragma unroll
    for (int u = 0; u < 16; u++) vals[u] = T[c_ + u][r_];
    *(uint4*)&Wt[(size_t)(n0 + r_) * K + k0 + c_] = *(uint4*)&vals[0];
    *(uint4*)&Wt[(size_t)(n0 + r_) * K + k0 + c_ + 8] = *(uint4*)&vals[8];
}

// ---------------------------------------------------------------- fused projections
// One launch, 768 blocks, 128x128 tiles, K=1024, m97-style staging.
// blocks [0,512): kv-proj -> kh [b][n][j][d], vt [b][n][d][j]
// blocks [512,640): q-proj -> qw(+rwb), qr(+rrb) head-split
// blocks [640,768): r-proj -> rk [n][t][d]
// V-blocks (tx>=8) transpose C through LDS -> coalesced vt stores.
__global__ __launch_bounds__(256) void proj_fused(
    const half_t* __restrict__ wh, const half_t* __restrict__ rh,
    const half_t* __restrict__ WqT, const half_t* __restrict__ WkvT,
    const half_t* __restrict__ WrT,
    half_t* __restrict__ qw, half_t* __restrict__ qr,
    half_t* __restrict__ kh, half_t* __restrict__ vt,
    half_t* __restrict__ rk,
    const float* __restrict__ rwb, const float* __restrict__ rrb) {
    // staging (2x 128x64 = 32KB) aliased with transpose buffer (128x136 = 34KB)
    __shared__ __attribute__((aligned(16))) half_t SM[128 * 136];
    half_t (*As)[64] = (half_t(*)[64])SM;
    half_t (*Bs)[64] = (half_t(*)[64])(SM + 128 * 64);
    half_t (*LT)[136] = (half_t(*)[136])SM;

    int bid = blockIdx.x;
    int mode, tx, ty;
    const half_t* A; const half_t* Bt;
    if (bid < 512)      { mode = 1; tx = bid & 15, ty = bid >> 4; A = wh; Bt = WkvT; }
    else if (bid < 640) { int c = bid - 512; mode = 0; tx = c & 7; ty = c >> 3;
                          A = wh + (size_t)QLENC * BSZC * DMODELC; Bt = WqT; }
    else                { int c = bid - 640; mode = 2; tx = c & 7; ty = c >> 3;
                          A = rh; Bt = WrT; }

    int t = threadIdx.x;
    int w = t >> 6, ln = t & 63, quad = ln >> 4, l15 = ln & 15;
    int m0 = ty * 128, n0 = tx * 128;
    int rbase = 64 * (w >> 1), cbase = 64 * (w & 1);
    int lrow = ln >> 3, lcol = (ln & 7) * 8;

    f32x4 acc[4][4];
#pragma unroll
    for (int i = 0; i < 4; i++)
#pragma unroll
        for (int j = 0; j < 4; j++) acc[i][j] = (f32x4){0.f, 0.f, 0.f, 0.f};

    for (int k0 = 0; k0 < 1024; k0 += 64) {
        __syncthreads();
#pragma unroll
        for (int j = 0; j < 4; j++) {
            int r8 = w * 32 + j * 8;
            async_copy16(&A[(size_t)(m0 + r8 + lrow) * 1024 + k0 + lcol], &As[r8][0]);
            async_copy16(&Bt[(size_t)(n0 + r8 + lrow) * 1024 + k0 + lcol], &Bs[r8][0]);
        }
        __syncthreads();
#pragma unroll
        for (int kk = 0; kk < 2; kk++) {
            f16x8 af[4], bfr[4];
#pragma unroll
            for (int rb = 0; rb < 4; rb++)
                af[rb] = *(const f16x8*)&As[rbase + rb * 16 + l15][kk * 32 + quad * 8];
#pragma unroll
            for (int cb = 0; cb < 4; cb++)
                bfr[cb] = *(const f16x8*)&Bs[cbase + cb * 16 + l15][kk * 32 + quad * 8];
#pragma unroll
            for (int rb = 0; rb < 4; rb++)
#pragma unroll
                for (int cb = 0; cb < 4; cb++)
                    acc[rb][cb] = __builtin_amdgcn_mfma_f32_16x16x32_f16(
                        af[rb], bfr[cb], acc[rb][cb], 0, 0, 0);
        }
    }

    if (mode == 1 && tx >= 8) {
        // V-block: transpose C through LDS, store vt coalesced.
        __syncthreads();  // staging reads done; safe to overwrite SM
#pragma unroll
        for (int rb = 0; rb < 4; rb++)
#pragma unroll
            for (int cb = 0; cb < 4; cb++)
#pragma unroll
                for (int reg = 0; reg < 4; reg++) {
                    int lr_ = rbase + 16 * rb + quad * 4 + reg;  // m-dir 0..127
                    int lc_ = cbase + 16 * cb + l15;             // n-dir 0..127
                    LT[lc_][lr_] = (half_t)acc[rb][cb][reg];
                }
        __syncthreads();
        // 8 passes; 8 lanes per (lc_, b) pair write one 128B p-run as uint4s.
#pragma unroll
        for (int pass = 0; pass < 8; pass++) {
            int g = pass * 32 + (t >> 3), s_ = t & 7;
            int lc_ = g >> 1, b_ = g & 1;
            half_t tmp[8];
#pragma unroll
            for (int k = 0; k < 8; k++) tmp[k] = LT[lc_][b_ + 2 * (s_ * 8 + k)];
            int gc = n0 - 1024 + lc_;
            int hh = gc >> 6, d_ = gc & 63;
            int p0 = (m0 >> 1) + s_ * 8;
            *(uint4*)&vt[(((size_t)(b_ * NHC + hh)) * DHC + d_) * KLENC + p0] = *(uint4*)&tmp[0];
        }
        return;
    }

#pragma unroll
    for (int rb = 0; rb < 4; rb++)
#pragma unroll
        for (int cb = 0; cb < 4; cb++)
#pragma unroll
            for (int reg = 0; reg < 4; reg++) {
                int gr = m0 + rbase + 16 * rb + quad * 4 + reg;
                int gc = n0 + cbase + 16 * cb + l15;
                float v = acc[rb][cb][reg];
                if (mode == 1) {
                    int p_ = gr >> 1, b_ = gr & 1;
                    int n_ = gc >> 6, d_ = gc & 63;
                    kh[(((size_t)(b_ * NHC + n_)) * KLENC + p_) * DHC + d_] = (half_t)v;
                } else if (mode == 0) {
                    int p_ = gr >> 1, b_ = gr & 1, n_ = gc >> 6, d_ = gc & 63;
                    size_t idx = (((size_t)(b_ * NHC + n_)) * QLENC + p_) * DHC + d_;
                    qw[idx] = (half_t)(v + rwb[gc]);
                    qr[idx] = (half_t)(v + rrb[gc]);
                } else {
                    int n_ = gc >> 6, d_ = gc & 63;
                    rk[(((size_t)n_) * KLENC + gr) * DHC + d_] = (half_t)v;
                }
            }
}

// ---------------------------------------------------------------- out GEMM
// 64x128 tiles, grid (8,32) = 256 blocks = 1/CU (was 128 blocks = half GPU
// idle). As 64x64 + Bs 128x64 = 24KB LDS; per-wave 32x64 output acc[2][4].
__global__ __launch_bounds__(256) void gemm_out(
    const half_t* __restrict__ A, const half_t* __restrict__ Bt,
    float* __restrict__ o) {
    __shared__ __attribute__((aligned(16))) half_t As[64][64];
    __shared__ __attribute__((aligned(16))) half_t Bs[128][64];

    int t = threadIdx.x;
    int w = t >> 6, ln = t & 63, quad = ln >> 4, l15 = ln & 15;
    int m0 = blockIdx.y * 64, n0 = blockIdx.x * 128;
    int rbase = 32 * (w >> 1), cbase = 64 * (w & 1);
    int lrow = ln >> 3, lcol = (ln & 7) * 8;

    f32x4 acc[2][4];
#pragma unroll
    for (int i = 0; i < 2; i++)
#pragma unroll
        for (int j = 0; j < 4; j++) acc[i][j] = (f32x4){0.f, 0.f, 0.f, 0.f};

    for (int k0 = 0; k0 < 1024; k0 += 64) {
        __syncthreads();
#pragma unroll
        for (int j = 0; j < 2; j++) {
            int r8 = w * 16 + j * 8;  // wave w stages A rows [w*16, w*16+16)
            async_copy16(&A[(size_t)(m0 + r8 + lrow) * 1024 + k0 + lcol], &As[r8][0]);
        }
#pragma unroll
        for (int j = 0; j < 4; j++) {
            int r8 = w * 32 + j * 8;  // wave w stages B rows [w*32, w*32+32)
            async_copy16(&Bt[(size_t)(n0 + r8 + lrow) * 1024 + k0 + lcol], &Bs[r8][0]);
        }
        __syncthreads();
#pragma unroll
        for (int kk = 0; kk < 2; kk++) {
            f16x8 af[2], bfr[4];
#pragma unroll
            for (int rb = 0; rb < 2; rb++)
                af[rb] = *(const f16x8*)&As[rbase + rb * 16 + l15][kk * 32 + quad * 8];
#pragma unroll
            for (int cb = 0; cb < 4; cb++)
                bfr[cb] = *(const f16x8*)&Bs[cbase + cb * 16 + l15][kk * 32 + quad * 8];
#pragma unroll
            for (int rb = 0; rb < 2; rb++)
#pragma unroll
                for (int cb = 0; cb < 4; cb++)
                    acc[rb][cb] = __builtin_amdgcn_mfma_f32_16x16x32_f16(
                        af[rb], bfr[cb], acc[rb][cb], 0, 0, 0);
        }
    }

#pragma unroll
    for (int rb = 0; rb < 2; rb++)
#pragma unroll
        for (int cb = 0; cb < 4; cb++)
#pragma unroll
            for (int reg = 0; reg < 4; reg++) {
                int gr = m0 + rbase + 16 * rb + quad * 4 + reg;
                int gc = n0 + cbase + 16 * cb + l15;
                o[(size_t)gr * 1024 + gc] = acc[rb][cb][reg];
            }
}

// ---------------------------------------------------------------- fused attention
// One block per (head, 64-row q tile, batch, K-split s). Split s handles
// jt in [s*16, s*16+16). Body is the round-4 102us structure VERBATIM:
// K/V/RK reg-staged into LDS, 2 barriers/tile, next-tile prefetch after s2.
// Windowed T = Qr @ rk[window]^T implements rel_shift:
//   delta = j-i: delta<=1024 -> qr_i . rk[1023+delta]   (window mb = 960+D)
//                delta==1025 -> 0
//                delta>=1026 -> qr_{i+1} . rk[delta-1026] (window mb = D-1089)
// Wave w computes T col-tiles {3-w..7-w}; per-wave TP[16][88], local col =
// 15+jc-ic_local. No-max softmax: p = exp(s) raw; partial unnormalized f32 O
// + row sums stored; combine kernel normalizes (exact).
__global__ __launch_bounds__(256, 3) void attn_fused(
    const half_t* __restrict__ qw, const half_t* __restrict__ qr,
    const half_t* __restrict__ kh, const half_t* __restrict__ vt,
    const half_t* __restrict__ rk, float* __restrict__ po,
    float* __restrict__ pl) {
    __shared__ __attribute__((aligned(16))) half_t Ks[64][72];
    __shared__ __attribute__((aligned(16))) half_t Vs[64][72];
    __shared__ __attribute__((aligned(16))) half_t RKs[128][72];
    __shared__ __attribute__((aligned(16))) half_t TP[4][16][88];

    int n = blockIdx.x, i0 = blockIdx.y * 64;
    int z = blockIdx.z, b = z >> 1, s = z & 1;
    int jt0 = s * 16, jt1 = jt0 + 16;
    int t = threadIdx.x, w = t >> 6, ln = t & 63, quad = ln >> 4, l15 = ln & 15;
    int lr = t >> 2, lc = (t & 3) << 4;
    int q4 = quad * 4;            // local row base within the wave's 16 rows
    int wq = w * 16 + q4;
    size_t bn = (size_t)(b * NHC + n);
    const half_t* rkn = rk + (size_t)n * KLENC * DHC;
    half_t (*TPw)[88] = TP[w];

    // Q/Qr fragments: wave-local rows -> registers, loaded once per block.
    f16x8 aqw[2], aq1[2], aq2[2];
    {
        int row1 = i0 + w * 16 + l15;
        int row2 = row1 + 1; if (row2 > QLENC - 1) row2 = QLENC - 1;  // clamped row never contributes
#pragma unroll
        for (int kk = 0; kk < 2; kk++) {
            aqw[kk] = *(const f16x8*)&qw[((bn * QLENC) + row1) * DHC + kk * 32 + quad * 8];
            aq1[kk] = *(const f16x8*)&qr[((bn * QLENC) + row1) * DHC + kk * 32 + quad * 8];
            aq2[kk] = *(const f16x8*)&qr[((bn * QLENC) + row2) * DHC + kk * 32 + quad * 8];
        }
    }

    int rrl = t >> 1, rh = (t & 1) * 32;

    // prefetch tile jt0
    uint4 pk0, pk1, pv0, pv1, pr0, pr1, pr2, pr3;
    {
        int j0 = jt0 * 64;
        int D = j0 - i0;
        int mb = (D <= 1024) ? (960 + D) : (D - 1089);
        int rrow = mb + rrl; rrow = rrow < 0 ? 0 : (rrow > KLENC - 1 ? KLENC - 1 : rrow);
        const uint4* ks = (const uint4*)&kh[((bn * KLENC) + j0 + lr) * DHC + lc];
        const uint4* vs = (const uint4*)&vt[((bn * DHC) + lr) * KLENC + j0 + lc];
        pk0 = ks[0]; pk1 = ks[1]; pv0 = vs[0]; pv1 = vs[1];
        const uint4* rs = (const uint4*)&rkn[(size_t)rrow * DHC + rh];
        pr0 = rs[0]; pr1 = rs[1]; pr2 = rs[2]; pr3 = rs[3];
    }

    f32x4 O[4];
#pragma unroll
    for (int i = 0; i < 4; i++) O[i] = (f32x4){0.f, 0.f, 0.f, 0.f};
    float lsum[4] = {0.f, 0.f, 0.f, 0.f};
    const float scale = 0.125f;  // 1/sqrt(64)

    for (int jt = jt0; jt < jt1; jt++) {
        int j0 = jt * 64;
        int D = j0 - i0;
        bool need1 = (D <= 1024), need2 = (D >= 1024);  // block-uniform

        __syncthreads();  // s1: prior-iter cross-wave LDS reads done (drains prefetch vmcnt)
        *(uint4*)&Ks[lr][lc] = pk0; *(uint4*)&Ks[lr][lc + 8] = pk1;
        *(uint4*)&Vs[lr][lc] = pv0; *(uint4*)&Vs[lr][lc + 8] = pv1;
        *(uint4*)&RKs[rrl][rh] = pr0;      *(uint4*)&RKs[rrl][rh + 8] = pr1;
        *(uint4*)&RKs[rrl][rh + 16] = pr2; *(uint4*)&RKs[rrl][rh + 24] = pr3;
        __syncthreads();  // s2

        // T14: issue next tile's loads NOW; latency hides under this tile's compute
        if (jt + 1 < jt1) {
            int j0n = j0 + 64, Dn = j0n - i0;
            int mbn = (Dn <= 1024) ? (960 + Dn) : (Dn - 1089);
            int rrown = mbn + rrl; rrown = rrown < 0 ? 0 : (rrown > KLENC - 1 ? KLENC - 1 : rrown);
            const uint4* ks = (const uint4*)&kh[((bn * KLENC) + j0n + lr) * DHC + lc];
            const uint4* vs = (const uint4*)&vt[((bn * DHC) + lr) * KLENC + j0n + lc];
            pk0 = ks[0]; pk1 = ks[1]; pv0 = vs[0]; pv1 = vs[1];
            const uint4* rs = (const uint4*)&rkn[(size_t)rrown * DHC + rh];
            pr0 = rs[0]; pr1 = rs[1]; pr2 = rs[2]; pr3 = rs[3];
        }

        f32x4 sa[4];
#pragma unroll
        for (int cb = 0; cb < 4; cb++) sa[cb] = (f32x4){0.f, 0.f, 0.f, 0.f};
#pragma unroll
        for (int kk = 0; kk < 2; kk++) {
#pragma unroll
            for (int cb = 0; cb < 4; cb++) {
                f16x8 bk = *(const f16x8*)&Ks[cb * 16 + l15][kk * 32 + quad * 8];
                sa[cb] = __builtin_amdgcn_mfma_f32_16x16x32_f16(aqw[kk], bk, sa[cb], 0, 0, 0);
            }
        }

        float bdv[4][4];
#pragma unroll
        for (int cb = 0; cb < 4; cb++)
#pragma unroll
            for (int reg = 0; reg < 4; reg++) bdv[cb][reg] = 0.f;

        if (need1) {
            f32x4 tacc[5];
#pragma unroll
            for (int c = 0; c < 5; c++) tacc[c] = (f32x4){0.f, 0.f, 0.f, 0.f};
#pragma unroll
            for (int kk = 0; kk < 2; kk++) {
#pragma unroll
                for (int c = 0; c < 5; c++) {
                    f16x8 bk = *(const f16x8*)&RKs[(3 - w + c) * 16 + l15][kk * 32 + quad * 8];
                    tacc[c] = __builtin_amdgcn_mfma_f32_16x16x32_f16(aq1[kk], bk, tacc[c], 0, 0, 0);
                }
            }
            // wave-local write -> gather (per-wave TP, local col = c*16+l15)
#pragma unroll
            for (int c = 0; c < 5; c++)
#pragma unroll
                for (int reg = 0; reg < 4; reg++)
                    TPw[q4 + reg][c * 16 + l15] = (half_t)tacc[c][reg];
#pragma unroll
            for (int reg = 0; reg < 4; reg++) {
                int icl = q4 + reg, ic = w * 16 + icl;
#pragma unroll
                for (int cb = 0; cb < 4; cb++) {
                    int jc = cb * 16 + l15;
                    int delta = D + jc - ic;
                    if (delta <= 1024) bdv[cb][reg] = (float)TPw[icl][15 + jc - icl];
                }
            }
        }
        if (need2) {
            if (need1) {  // mixed tile (D==1024): restage window 2 (cross-wave)
                int mb2 = D - 1089;
                int rrow2 = mb2 + rrl; rrow2 = rrow2 < 0 ? 0 : (rrow2 > KLENC - 1 ? KLENC - 1 : rrow2);
                const uint4* rs2 = (const uint4*)&rkn[(size_t)rrow2 * DHC + rh];
                uint4 t0 = rs2[0], t1 = rs2[1], t2 = rs2[2], t3 = rs2[3];
                __syncthreads();
                *(uint4*)&RKs[rrl][rh] = t0;      *(uint4*)&RKs[rrl][rh + 8] = t1;
                *(uint4*)&RKs[rrl][rh + 16] = t2; *(uint4*)&RKs[rrl][rh + 24] = t3;
                __syncthreads();
            }
            f32x4 tacc[5];
#pragma unroll
            for (int c = 0; c < 5; c++) tacc[c] = (f32x4){0.f, 0.f, 0.f, 0.f};
#pragma unroll
            for (int kk = 0; kk < 2; kk++) {
#pragma unroll
                for (int c = 0; c < 5; c++) {
                    f16x8 bk = *(const f16x8*)&RKs[(3 - w + c) * 16 + l15][kk * 32 + quad * 8];
                    tacc[c] = __builtin_amdgcn_mfma_f32_16x16x32_f16(aq2[kk], bk, tacc[c], 0, 0, 0);
                }
            }
#pragma unroll
            for (int c = 0; c < 5; c++)
#pragma unroll
                for (int reg = 0; reg < 4; reg++)
                    TPw[q4 + reg][c * 16 + l15] = (half_t)tacc[c][reg];
#pragma unroll
            for (int reg = 0; reg < 4; reg++) {
                int icl = q4 + reg, ic = w * 16 + icl;
#pragma unroll
                for (int cb = 0; cb < 4; cb++) {
                    int jc = cb * 16 + l15;
                    int delta = D + jc - ic;
                    if (delta >= 1026) bdv[cb][reg] = (float)TPw[icl][15 + jc - icl];
                }
            }
        }

        // no-max softmax: p = exp(score), straight accumulate
        float p[4][4];
#pragma unroll
        for (int reg = 0; reg < 4; reg++) {
            float ps = 0.f;
#pragma unroll
            for (int cb = 0; cb < 4; cb++) {
                float e = __expf((sa[cb][reg] + bdv[cb][reg]) * scale);
                e = fminf(e, 60000.f);  // fp16-inf insurance
                p[cb][reg] = e; ps += e;
            }
            lsum[reg] += ps;
        }

        // P: wave-local C-layout -> A-layout round trip (no barrier)
#pragma unroll
        for (int cb = 0; cb < 4; cb++)
#pragma unroll
            for (int reg = 0; reg < 4; reg++)
                TPw[q4 + reg][cb * 16 + l15] = (half_t)p[cb][reg];
#pragma unroll
        for (int kk = 0; kk < 2; kk++) {
            f16x8 pa = *(const f16x8*)&TPw[l15][kk * 32 + quad * 8];
#pragma unroll
            for (int db = 0; db < 4; db++) {
                f16x8 vb = *(const f16x8*)&Vs[db * 16 + l15][kk * 32 + quad * 8];
                O[db] = __builtin_amdgcn_mfma_f32_16x16x32_f16(pa, vb, O[db], 0, 0, 0);
            }
        }
    }

    // store unnormalized partials: po[s][bn][i][d] f32, pl[s][bn][i] row-sums
    size_t pobase = ((size_t)s * 32 + bn) * QLENC;
#pragma unroll
    for (int db = 0; db < 4; db++)
#pragma unroll
        for (int reg = 0; reg < 4; reg++)
            po[(pobase + i0 + wq + reg) * 64 + db * 16 + l15] = O[db][reg];
#pragma unroll
    for (int reg = 0; reg < 4; reg++) {
        float tot = lsum[reg];
#pragma unroll
        for (int off = 1; off < 16; off <<= 1) tot += __shfl_xor(tot, off, 64);
        if (l15 == 0) pl[pobase + i0 + wq + reg] = tot;
    }
}

// ---------------------------------------------------------------- combine
// av[i][b][n*64+d] = (po0 + po1) / (pl0 + pl1). 262144 threads, 8 d each.
__global__ __launch_bounds__(256) void combine(
    const float* __restrict__ po, const float* __restrict__ pl,
    half_t* __restrict__ av) {
    int gid = blockIdx.x * 256 + threadIdx.x;
    int d0 = (gid & 7) * 8;
    int i = (gid >> 3) & 1023;
    int bn = gid >> 13;
    size_t rowoff = (size_t)bn * QLENC + i;
    size_t base = rowoff * 64 + d0;
    const size_t S = (size_t)32 * QLENC * 64;
    float4 a0 = *(const float4*)&po[base];
    float4 a1 = *(const float4*)&po[base + 4];
    float4 b0 = *(const float4*)&po[S + base];
    float4 b1 = *(const float4*)&po[S + base + 4];
    float invl = 1.0f / (pl[rowoff] + pl[(size_t)32 * QLENC + rowoff]);
    half_t h[8];
    h[0] = (half_t)((a0.x + b0.x) * invl); h[1] = (half_t)((a0.y + b0.y) * invl);
    h[2] = (half_t)((a0.z + b0.z) * invl); h[3] = (half_t)((a0.w + b0.w) * invl);
    h[4] = (half_t)((a1.x + b1.x) * invl); h[5] = (half_t)((a1.y + b1.y) * invl);
    h[6] = (half_t)((a1.z + b1.z) * invl); h[7] = (half_t)((a1.w + b1.w) * invl);
    int b = bn >> 4, n = bn & 15;
    *(uint4*)&av[((size_t)i * BSZC + b) * DMODELC + n * 64 + d0] = *(uint4*)&h[0];
}

// ---------------------------------------------------------------- launch
extern "C" void kernel_launch(void* const* d_in, const int* in_sizes, int n_in,
                              void* d_out, int out_size, void* d_ws, size_t ws_size,
                              hipStream_t stream) {
    const float* w   = (const float*)d_in[0];
    const float* r   = (const float*)d_in[1];
    const float* rwb = (const float*)d_in[2];
    const float* rrb = (const float*)d_in[3];
    const float* Wq  = (const float*)d_in[4];
    const float* Wkv = (const float*)d_in[5];
    const float* Wr  = (const float*)d_in[6];
    const float* Wo  = (const float*)d_in[7];
    float* out = (float*)d_out;

    half_t* ws = (half_t*)d_ws;
    half_t* qw   = ws; ws += (size_t)BSZC * NHC * QLENC * DHC;
    half_t* qr   = ws; ws += (size_t)BSZC * NHC * QLENC * DHC;
    half_t* kh   = ws; ws += (size_t)BSZC * NHC * KLENC * DHC;
    half_t* vt   = ws; ws += (size_t)BSZC * NHC * KLENC * DHC;
    half_t* rk   = ws; ws += (size_t)NHC * KLENC * DHC;
    half_t* av   = ws; ws += (size_t)QLENC * BSZC * DMODELC;
    half_t* WoT  = ws; ws += (size_t)DMODELC * DMODELC;   // live through gemm_out
    half_t* WqT  = ws; ws += (size_t)DMODELC * DMODELC;   // dead after proj_fused
    half_t* WkvT = ws; ws += (size_t)2 * DMODELC * DMODELC;
    half_t* WrT  = ws; ws += (size_t)DMODELC * DMODELC;
    half_t* wh   = ws; ws += (size_t)KLENC * BSZC * DMODELC;
    half_t* rh   = ws; ws += (size_t)KLENC * DMODELC;

    // attn partials alias the dead region WqT..rh (20MB >= 16.25MB needed):
    // po: 2 splits x 32 bn x 1024 i x 64 d f32 (16MB), pl: 2x32x1024 f32.
    float* po = (float*)WqT;
    float* pl = po + (size_t)2 * 32 * QLENC * 64;

    dim3 blk(256);
    prep<<<dim3(4352), blk, 0, stream>>>(w, r, Wq, Wkv, Wr, Wo,
                                         wh, rh, WqT, WkvT, WrT, WoT);
    proj_fused<<<dim3(768), blk, 0, stream>>>(
        wh, rh, WqT, WkvT, WrT, qw, qr, kh, vt, rk, rwb, rrb);
    attn_fused<<<dim3(NHC, QLENC / 64, BSZC * 2), blk, 0, stream>>>(
        qw, qr, kh, vt, rk, po, pl);
    combine<<<dim3(1024), blk, 0, stream>>>(po, pl, av);
    gemm_out<<<dim3(8, 32), blk, 0, stream>>>(av, WoT, out);

    (void)in_sizes; (void)n_in; (void)out_size; (void)ws_size;
}